// Round 5
// baseline (445.847 us; speedup 1.0000x reference)
//
#include <hip/hip_runtime.h>

#define S_ 4
#define C_ 256
#define CE_ 128
#define KD_ 128
#define HW_ 1024
#define T_ 8
#define M_ 8192
#define NSPLIT 4
#define KSPLIT 2048          // M_ / NSPLIT
#define KTILES 32            // KSPLIT / 64
#define NEGINF -3.0e38f
#define LOG2E 1.4426950408889634f
#define SQRT30 5.4772255750516612f

typedef short bf16x8 __attribute__((ext_vector_type(8)));
typedef float f32x16 __attribute__((ext_vector_type(16)));

#define MFMA32(a, b, c) __builtin_amdgcn_mfma_f32_32x32x16_bf16(a, b, c, 0, 0, 0)

// ---------------- workspace layout (float offsets) ----------------
// live through self+proj phase:
//   PFT 0        (524288)   tgt P frags (*sqrt30)      dead after self_flash
//   XV  524288   (1048576)  tgt channel-value granules dead after self_flash
//   Z   1572864  (1048576)  self-attn out + residual   dead after inorm
//   ZN  2621440  (1048576)  instance-normed            dead after proj_frag(Zn)
//   QF  3670016  (524288)   cross Q frags (*30)        live into cross_flash
//   KF  4194304  (4194304)  cross K frags (memory)     live into cross_flash
//   VF  8388608  (4194304)  cross V frags (pos_enc)    live into cross_flash
// total 12582912 floats = 50.3 MB
// cross-phase overlays (PFT/XV/Z all dead before cross_flash writes these):
//   OPART 0        (NSPLIT*S*HW*CE = 2097152)
//   MPART 2097152  (NSPLIT*S*HW = 16384)
//   LPART 2113536  (16384)  -> ends 2129920 < 2621440 (inside dead PFT+XV+Z)
#define O_PFT   0u
#define O_XV    524288u
#define O_Z     1572864u
#define O_ZN    2621440u
#define O_QF    3670016u
#define O_KF    4194304u
#define O_VF    8388608u
#define O_OPART 0u
#define O_MPART 2097152u
#define O_LPART 2113536u

__device__ __forceinline__ bf16x8 u4_to_b8(uint4 u) {
    union { uint4 u; bf16x8 b; } c; c.u = u; return c.b;
}

__device__ __forceinline__ unsigned cvt_pk_bf16(float a, float b) {
    unsigned r;
    asm("v_cvt_pk_bf16_f32 %0, %1, %2" : "=v"(r) : "v"(a), "v"(b));
    return r;
}

// ============================================================================
// GEMM + bias + l2norm, output as hi/lo bf16 MFMA fragment granules:
// [s][rb32][hilo][dstep8][lane64*16B]. Element (r,d): lane=(r&31)|(((d>>3)&1)<<5),
// byte=(d&7)*2. Used for self-P (tgt), cross-Q (Zn), cross-K (memory).
// ============================================================================
__global__ __launch_bounds__(256)
void proj_frag_kernel(const float* __restrict__ src, const float* __restrict__ Wm,
                      const float* __restrict__ bias, char* __restrict__ outF,
                      int R, float scale)
{
    __shared__ float Xs[32][65];
    __shared__ float Ws[32][129];
    const int s  = blockIdx.y;
    const int r0 = blockIdx.x * 64;
    const int t  = r0 >> 10;
    const int l0 = r0 & 1023;
    const int tid = threadIdx.x;
    const int tx = tid & 15, ty = tid >> 4;
    const float* xb = src + ((size_t)(t * S_ + s) * C_) * HW_ + l0;

    float acc[4][8];
#pragma unroll
    for (int i = 0; i < 4; ++i)
#pragma unroll
        for (int j = 0; j < 8; ++j) acc[i][j] = 0.f;

    for (int c0 = 0; c0 < C_; c0 += 32) {
#pragma unroll
        for (int j = 0; j < 8; ++j) {
            int idx = tid + j * 256;
            Xs[idx >> 6][idx & 63] = xb[(size_t)(c0 + (idx >> 6)) * HW_ + (idx & 63)];
        }
#pragma unroll
        for (int j = 0; j < 16; ++j) {
            int idx = tid + j * 256;
            Ws[idx & 31][idx >> 5] = Wm[(idx >> 5) * C_ + c0 + (idx & 31)];
        }
        __syncthreads();
        for (int cc = 0; cc < 32; ++cc) {
            float xv[4], wv[8];
#pragma unroll
            for (int i = 0; i < 4; ++i) xv[i] = Xs[cc][ty * 4 + i];
#pragma unroll
            for (int j = 0; j < 8; ++j) wv[j] = Ws[cc][tx * 8 + j];
#pragma unroll
            for (int i = 0; i < 4; ++i)
#pragma unroll
                for (int j = 0; j < 8; ++j) acc[i][j] = fmaf(xv[i], wv[j], acc[i][j]);
        }
        __syncthreads();
    }

    float bv[8];
#pragma unroll
    for (int j = 0; j < 8; ++j) bv[j] = bias[tx * 8 + j];

    const int RB = R >> 5;
#pragma unroll
    for (int i = 0; i < 4; ++i) {
        float ss = 0.f;
#pragma unroll
        for (int j = 0; j < 8; ++j) {
            acc[i][j] += bv[j];
            ss = fmaf(acc[i][j], acc[i][j], ss);
        }
#pragma unroll
        for (int m = 1; m < 16; m <<= 1) ss += __shfl_xor(ss, m);
        float sc = scale / fmaxf(sqrtf(ss), 1e-12f);
        int r = r0 + ty * 4 + i;
        float v[8];
#pragma unroll
        for (int j = 0; j < 8; ++j) v[j] = acc[i][j] * sc;
        unsigned hp[4], lp[4];
#pragma unroll
        for (int p = 0; p < 4; ++p) {
            hp[p] = cvt_pk_bf16(v[2 * p], v[2 * p + 1]);
            float f0 = __uint_as_float(hp[p] << 16);
            float f1 = __uint_as_float(hp[p] & 0xffff0000u);
            lp[p] = cvt_pk_bf16(v[2 * p] - f0, v[2 * p + 1] - f1);
        }
        int lane = (r & 31) | ((tx & 1) << 5);
        int ds = tx >> 1;
        size_t gb = ((((size_t)s * RB + (r >> 5)) * 2 + 0) * 8 + ds) * 1024 + (size_t)lane * 16;
        *(uint4*)(outF + gb) = make_uint4(hp[0], hp[1], hp[2], hp[3]);
        *(uint4*)(outF + gb + 8 * 1024) = make_uint4(lp[0], lp[1], lp[2], lp[3]);
    }
}

// ============================================================================
// pe (T,S,128e,1024l) -> cross-V granules [s][kb16][hilo][etile4][1KB]
// Element (k,e): lane=(e&31)|(((k>>3)&1)<<5), byte=(k&7)*2.
// ============================================================================
__global__ __launch_bounds__(256)
void vconv_kernel(const float* __restrict__ pe, char* __restrict__ VF)
{
    int gid = blockIdx.x * 256 + threadIdx.x;   // 2^19 threads
    int lg = gid & 127;
    int e  = (gid >> 7) & 127;
    int s  = (gid >> 14) & 3;
    int t  = gid >> 16;
    int l0 = lg * 8;
    const float* p = pe + (((size_t)(t * S_ + s) * CE_ + e) * HW_ + l0);
    float4 va = ((const float4*)p)[0];
    float4 vb = ((const float4*)p)[1];
    float v[8] = {va.x, va.y, va.z, va.w, vb.x, vb.y, vb.z, vb.w};
    unsigned hp[4], lp[4];
#pragma unroll
    for (int q = 0; q < 4; ++q) {
        hp[q] = cvt_pk_bf16(v[2 * q], v[2 * q + 1]);
        float f0 = __uint_as_float(hp[q] << 16);
        float f1 = __uint_as_float(hp[q] & 0xffff0000u);
        lp[q] = cvt_pk_bf16(v[2 * q] - f0, v[2 * q + 1] - f1);
    }
    int k = t * 1024 + l0;
    int kb16 = k >> 4;
    int lane = (e & 31) | (((l0 >> 3) & 1) << 5);
    int et = e >> 5;
    size_t gb = ((((size_t)s * 512 + kb16) * 2 + 0) * 4 + et) * 1024 + (size_t)lane * 16;
    *(uint4*)(VF + gb) = make_uint4(hp[0], hp[1], hp[2], hp[3]);
    *(uint4*)(VF + gb + 4 * 1024) = make_uint4(lp[0], lp[1], lp[2], lp[3]);
}

// ============================================================================
// tgt (s,256ch,1024l) -> self-V channel granules [s][kb16 64][hilo][cht8][1KB]
// Element (ch,k=l): lane=(ch&31)|(((k>>3)&1)<<5), byte=(k&7)*2.
// ============================================================================
__global__ __launch_bounds__(256)
void xconv_kernel(const float* __restrict__ X, char* __restrict__ XV)
{
    int gid = blockIdx.x * 256 + threadIdx.x;   // 131072 threads
    int lg = gid & 127;
    int ch = (gid >> 7) & 255;
    int s  = gid >> 15;
    int l0 = lg * 8;
    const float* p = X + (((size_t)s * C_ + ch) * HW_ + l0);
    float4 va = ((const float4*)p)[0];
    float4 vb = ((const float4*)p)[1];
    float v[8] = {va.x, va.y, va.z, va.w, vb.x, vb.y, vb.z, vb.w};
    unsigned hp[4], lp[4];
#pragma unroll
    for (int q = 0; q < 4; ++q) {
        hp[q] = cvt_pk_bf16(v[2 * q], v[2 * q + 1]);
        float f0 = __uint_as_float(hp[q] << 16);
        float f1 = __uint_as_float(hp[q] & 0xffff0000u);
        lp[q] = cvt_pk_bf16(v[2 * q] - f0, v[2 * q + 1] - f1);
    }
    int kb16 = l0 >> 4;
    int lane = (ch & 31) | (((l0 >> 3) & 1) << 5);
    int cht = ch >> 5;
    size_t gb = ((((size_t)s * 64 + kb16) * 2 + 0) * 8 + cht) * 1024 + (size_t)lane * 16;
    *(uint4*)(XV + gb) = make_uint4(hp[0], hp[1], hp[2], hp[3]);
    *(uint4*)(XV + gb + 8 * 1024) = make_uint4(lp[0], lp[1], lp[2], lp[3]);
}

// ============================================================================
// Fused MFMA flash SELF-attention + residual: Z = X + softmax(30*P.P^T).X^T
// Swapped scores (D col = q). PV: A-op = X-ch granules (rows=ch), B-op = packed
// P (cols=q) => O col=q: lane-local 1/lsum, coalesced (s,ch,q) stores.
// Grid (qt 8, cs 2, s 4) = 64 blocks, 4 waves; LDS 2 x 64KB double-buffer.
// ============================================================================
__global__ __launch_bounds__(256, 1)
void self_flash_mfma(const char* __restrict__ PF, const char* __restrict__ XV,
                     const float* __restrict__ X, float* __restrict__ Z)
{
    __shared__ __align__(16) char lds[2][65536];
    const int qt = blockIdx.x, cs = blockIdx.y, s = blockIdx.z;
    const int tid = threadIdx.x;
    const int wv = tid >> 6, lane = tid & 63;
    const int l31 = lane & 31;
    const bool hh = lane >= 32;
    const int qb32 = qt * 4 + wv;

    // wave's 32-q Q fragments (B operand) resident in registers
    uint4 QH[8], QL[8];
    {
        const char* qb = PF + (((size_t)s * 32 + qb32) * 2) * 8192;
#pragma unroll
        for (int ds = 0; ds < 8; ++ds) {
            QH[ds] = *(const uint4*)(qb + ds * 1024 + lane * 16);
            QL[ds] = *(const uint4*)(qb + 8192 + ds * 1024 + lane * 16);
        }
    }

    f32x16 O[4];
#pragma unroll
    for (int et = 0; et < 4; ++et)
#pragma unroll
        for (int i = 0; i < 16; ++i) O[et][i] = 0.f;
    float m = NEGINF, lsum = 0.f;

    auto STAGE = [&](int b, int kt) {
        int k0 = kt * 64;
#pragma unroll
        for (int i = 0; i < 16; ++i) {
            int g = wv * 16 + i;
            const char* src;
            if (g < 32) {
                int at = g >> 4, hl = (g >> 3) & 1, ds = g & 7;
                src = PF + ((((size_t)s * 32 + (k0 >> 5) + at) * 2 + hl) * 8 + ds) * 1024
                         + (size_t)lane * 16;
            } else {
                int g2 = g - 32, ks = g2 >> 3, hl = (g2 >> 2) & 1, et = g2 & 3;
                src = XV + ((((size_t)s * 64 + (k0 >> 4) + ks) * 2 + hl) * 8 + cs * 4 + et) * 1024
                         + (size_t)lane * 16;
            }
            char* dst = &lds[b][g * 1024];
            __builtin_amdgcn_global_load_lds(
                (const __attribute__((address_space(1))) void*)src,
                (__attribute__((address_space(3))) void*)dst, 16, 0, 0);
        }
    };

    STAGE(0, 0);
    __syncthreads();

    for (int kt = 0; kt < 16; ++kt) {
        const int b = kt & 1;
        if (kt < 15) STAGE(b ^ 1, kt + 1);
        const char* Bp = lds[b];

        // ---- scores: D = K * Q^T ----
        f32x16 a0, a1;
#pragma unroll
        for (int i = 0; i < 16; ++i) { a0[i] = 0.f; a1[i] = 0.f; }
#pragma unroll
        for (int ds = 0; ds < 8; ++ds) {
            bf16x8 kh0 = *(const bf16x8*)(Bp + (0 + ds) * 1024 + lane * 16);
            bf16x8 kl0 = *(const bf16x8*)(Bp + (8 + ds) * 1024 + lane * 16);
            bf16x8 kh1 = *(const bf16x8*)(Bp + (16 + ds) * 1024 + lane * 16);
            bf16x8 kl1 = *(const bf16x8*)(Bp + (24 + ds) * 1024 + lane * 16);
            bf16x8 qh = u4_to_b8(QH[ds]), ql = u4_to_b8(QL[ds]);
            a0 = MFMA32(kh0, qh, a0);
            a0 = MFMA32(kh0, ql, a0);
            a0 = MFMA32(kl0, qh, a0);
            a1 = MFMA32(kh1, qh, a1);
            a1 = MFMA32(kh1, ql, a1);
            a1 = MFMA32(kl1, qh, a1);
        }

        // ---- online softmax (q = lane&31, lane-local) ----
        float tmax = NEGINF;
#pragma unroll
        for (int i = 0; i < 16; ++i) tmax = fmaxf(tmax, fmaxf(a0[i], a1[i]));
        tmax = fmaxf(tmax, __shfl_xor(tmax, 32));
        float mnew = fmaxf(m, tmax);
        float alpha = exp2f((m - mnew) * LOG2E);
        float mn2 = mnew * LOG2E;
        float P[32];
        float tsum = 0.f;
#pragma unroll
        for (int i = 0; i < 16; ++i) { P[i] = exp2f(fmaf(a0[i], LOG2E, -mn2)); tsum += P[i]; }
#pragma unroll
        for (int i = 0; i < 16; ++i) { P[16 + i] = exp2f(fmaf(a1[i], LOG2E, -mn2)); tsum += P[16 + i]; }
        tsum += __shfl_xor(tsum, 32);
        lsum = lsum * alpha + tsum;
        m = mnew;

        // rescale O: col = q = lane&31 -> alpha is lane-local
#pragma unroll
        for (int et = 0; et < 4; ++et)
#pragma unroll
            for (int i = 0; i < 16; ++i) O[et][i] *= alpha;

        // ---- pack P into hi/lo bf16 pairs ----
        unsigned hpk[16], lpk[16];
#pragma unroll
        for (int p = 0; p < 16; ++p) {
            hpk[p] = cvt_pk_bf16(P[2 * p], P[2 * p + 1]);
            float f0 = __uint_as_float(hpk[p] << 16);
            float f1 = __uint_as_float(hpk[p] & 0xffff0000u);
            lpk[p] = cvt_pk_bf16(P[2 * p] - f0, P[2 * p + 1] - f1);
        }

        // ---- PV: O[ch][q] += X[ch][k] * P[k][q] ----
#pragma unroll
        for (int ks = 0; ks < 4; ++ks) {
            const int i0 = (ks >> 1) * 8 + (ks & 1) * 4;
            unsigned t0 = hh ? hpk[i0 + 2] : hpk[i0];
            unsigned u0 = hh ? hpk[i0] : hpk[i0 + 2];
            unsigned w0 = __shfl_xor(u0, 32);
            unsigned A0 = hh ? w0 : t0;
            unsigned A2 = hh ? t0 : w0;
            unsigned t1 = hh ? hpk[i0 + 3] : hpk[i0 + 1];
            unsigned u1 = hh ? hpk[i0 + 1] : hpk[i0 + 3];
            unsigned w1 = __shfl_xor(u1, 32);
            unsigned A1 = hh ? w1 : t1;
            unsigned A3 = hh ? t1 : w1;

            unsigned s0 = hh ? lpk[i0 + 2] : lpk[i0];
            unsigned v0 = hh ? lpk[i0] : lpk[i0 + 2];
            unsigned x0 = __shfl_xor(v0, 32);
            unsigned B0 = hh ? x0 : s0;
            unsigned B2 = hh ? s0 : x0;
            unsigned s1 = hh ? lpk[i0 + 3] : lpk[i0 + 1];
            unsigned v1 = hh ? lpk[i0 + 1] : lpk[i0 + 3];
            unsigned x1 = __shfl_xor(v1, 32);
            unsigned B1 = hh ? x1 : s1;
            unsigned B3 = hh ? s1 : x1;

            bf16x8 pa_hi = u4_to_b8(make_uint4(A0, A1, A2, A3));
            bf16x8 pa_lo = u4_to_b8(make_uint4(B0, B1, B2, B3));
#pragma unroll
            for (int et = 0; et < 4; ++et) {
                bf16x8 xh = *(const bf16x8*)(Bp + (32 + (ks * 2 + 0) * 4 + et) * 1024 + lane * 16);
                bf16x8 xl = *(const bf16x8*)(Bp + (32 + (ks * 2 + 1) * 4 + et) * 1024 + lane * 16);
                O[et] = MFMA32(xh, pa_hi, O[et]);
                O[et] = MFMA32(xl, pa_hi, O[et]);
                O[et] = MFMA32(xh, pa_lo, O[et]);
            }
        }
        __syncthreads();
    }

    // ---- epilogue: normalize (lane-local), add residual, coalesced store ----
    float inv = 1.f / lsum;
    int q = qb32 * 32 + l31;
#pragma unroll
    for (int et = 0; et < 4; ++et)
#pragma unroll
        for (int r = 0; r < 16; ++r) {
            int ch = cs * 128 + et * 32 + (r & 3) + 8 * (r >> 2) + (hh ? 4 : 0);
            size_t a = ((size_t)s * C_ + ch) * HW_ + q;
            Z[a] = O[et][r] * inv + X[a];
        }
}

// ============================================================================
// InstanceNorm over spatial (1024) per (s,ch); Z,Zn layout (s,ch,l)
// ============================================================================
__global__ __launch_bounds__(256)
void inorm_kernel(const float* __restrict__ Z, float* __restrict__ Zn)
{
    __shared__ float red[4];
    __shared__ float red2[4];
    const float* p = Z + (size_t)blockIdx.x * HW_;
    float* q = Zn + (size_t)blockIdx.x * HW_;
    const int tid = threadIdx.x;
    float4 x = ((const float4*)p)[tid];
    float sm = x.x + x.y + x.z + x.w;
#pragma unroll
    for (int m = 1; m < 64; m <<= 1) sm += __shfl_xor(sm, m);
    if ((tid & 63) == 0) red[tid >> 6] = sm;
    __syncthreads();
    float mu = (red[0] + red[1] + red[2] + red[3]) * (1.f / 1024.f);
    float dx0 = x.x - mu, dx1 = x.y - mu, dx2 = x.z - mu, dx3 = x.w - mu;
    float ss = dx0 * dx0 + dx1 * dx1 + dx2 * dx2 + dx3 * dx3;
#pragma unroll
    for (int m = 1; m < 64; m <<= 1) ss += __shfl_xor(ss, m);
    if ((tid & 63) == 0) red2[tid >> 6] = ss;
    __syncthreads();
    float var = (red2[0] + red2[1] + red2[2] + red2[3]) * (1.f / 1024.f);
    float inv = 1.f / sqrtf(var + 1e-5f);
    float4 o;
    o.x = dx0 * inv; o.y = dx1 * inv; o.z = dx2 * inv; o.w = dx3 * inv;
    ((float4*)q)[tid] = o;
}

// ============================================================================
// MFMA flash CROSS-attention. NSPLIT=4: split covers 2048 keys = 32 k-tiles.
// Grid (qt 8, split 4, s 4) = 128 blocks, 4 waves.
// ============================================================================
__global__ __launch_bounds__(256, 1)
void cross_flash_mfma(const char* __restrict__ QF, const char* __restrict__ KF,
                      const char* __restrict__ VF, float* __restrict__ Opart,
                      float* __restrict__ mpart, float* __restrict__ lpart)
{
    __shared__ __align__(16) char lds[2][65536];
    const int qt = blockIdx.x, split = blockIdx.y, s = blockIdx.z;
    const int tid = threadIdx.x;
    const int wv = tid >> 6, lane = tid & 63;
    const int l31 = lane & 31;
    const bool hh = lane >= 32;
    const int qb32 = qt * 4 + wv;

    uint4 QH[8], QL[8];
    {
        const char* qb = QF + (((size_t)s * 32 + qb32) * 2) * 8192;
#pragma unroll
        for (int ds = 0; ds < 8; ++ds) {
            QH[ds] = *(const uint4*)(qb + ds * 1024 + lane * 16);
            QL[ds] = *(const uint4*)(qb + 8192 + ds * 1024 + lane * 16);
        }
    }

    f32x16 O[4];
#pragma unroll
    for (int et = 0; et < 4; ++et)
#pragma unroll
        for (int i = 0; i < 16; ++i) O[et][i] = 0.f;
    float m = NEGINF, lsum = 0.f;

    const int k0base = split * KSPLIT;

    auto STAGE = [&](int b, int kt) {
        int k0 = k0base + kt * 64;
#pragma unroll
        for (int i = 0; i < 16; ++i) {
            int g = wv * 16 + i;
            const char* src;
            if (g < 32) {
                int at = g >> 4, hl = (g >> 3) & 1, ds = g & 7;
                src = KF + ((((size_t)s * 256 + (k0 >> 5) + at) * 2 + hl) * 8 + ds) * 1024
                         + (size_t)lane * 16;
            } else {
                int g2 = g - 32, ks = g2 >> 3, hl = (g2 >> 2) & 1, et = g2 & 3;
                src = VF + ((((size_t)s * 512 + (k0 >> 4) + ks) * 2 + hl) * 4 + et) * 1024
                         + (size_t)lane * 16;
            }
            char* dst = &lds[b][g * 1024];
            __builtin_amdgcn_global_load_lds(
                (const __attribute__((address_space(1))) void*)src,
                (__attribute__((address_space(3))) void*)dst, 16, 0, 0);
        }
    };

    STAGE(0, 0);
    __syncthreads();

    for (int kt = 0; kt < KTILES; ++kt) {
        const int b = kt & 1;
        if (kt < KTILES - 1) STAGE(b ^ 1, kt + 1);
        const char* Bp = lds[b];

        f32x16 a0, a1;
#pragma unroll
        for (int i = 0; i < 16; ++i) { a0[i] = 0.f; a1[i] = 0.f; }
#pragma unroll
        for (int ds = 0; ds < 8; ++ds) {
            bf16x8 kh0 = *(const bf16x8*)(Bp + (0 + ds) * 1024 + lane * 16);
            bf16x8 kl0 = *(const bf16x8*)(Bp + (8 + ds) * 1024 + lane * 16);
            bf16x8 kh1 = *(const bf16x8*)(Bp + (16 + ds) * 1024 + lane * 16);
            bf16x8 kl1 = *(const bf16x8*)(Bp + (24 + ds) * 1024 + lane * 16);
            bf16x8 qh = u4_to_b8(QH[ds]), ql = u4_to_b8(QL[ds]);
            a0 = MFMA32(kh0, qh, a0);
            a0 = MFMA32(kh0, ql, a0);
            a0 = MFMA32(kl0, qh, a0);
            a1 = MFMA32(kh1, qh, a1);
            a1 = MFMA32(kh1, ql, a1);
            a1 = MFMA32(kl1, qh, a1);
        }

        float tmax = NEGINF;
#pragma unroll
        for (int i = 0; i < 16; ++i) tmax = fmaxf(tmax, fmaxf(a0[i], a1[i]));
        tmax = fmaxf(tmax, __shfl_xor(tmax, 32));
        float mnew = fmaxf(m, tmax);
        float alpha = exp2f((m - mnew) * LOG2E);
        float mn2 = mnew * LOG2E;
        float P[32];
        float tsum = 0.f;
#pragma unroll
        for (int i = 0; i < 16; ++i) { P[i] = exp2f(fmaf(a0[i], LOG2E, -mn2)); tsum += P[i]; }
#pragma unroll
        for (int i = 0; i < 16; ++i) { P[16 + i] = exp2f(fmaf(a1[i], LOG2E, -mn2)); tsum += P[16 + i]; }
        tsum += __shfl_xor(tsum, 32);
        lsum = lsum * alpha + tsum;
        m = mnew;

#pragma unroll
        for (int r = 0; r < 16; ++r) {
            int qrow = (r & 3) + 8 * (r >> 2) + (hh ? 4 : 0);
            float ar = __shfl(alpha, qrow | (hh ? 32 : 0));
#pragma unroll
            for (int et = 0; et < 4; ++et) O[et][r] *= ar;
        }

        unsigned hpk[16], lpk[16];
#pragma unroll
        for (int p = 0; p < 16; ++p) {
            hpk[p] = cvt_pk_bf16(P[2 * p], P[2 * p + 1]);
            float f0 = __uint_as_float(hpk[p] << 16);
            float f1 = __uint_as_float(hpk[p] & 0xffff0000u);
            lpk[p] = cvt_pk_bf16(P[2 * p] - f0, P[2 * p + 1] - f1);
        }

#pragma unroll
        for (int ks = 0; ks < 4; ++ks) {
            const int i0 = (ks >> 1) * 8 + (ks & 1) * 4;
            unsigned t0 = hh ? hpk[i0 + 2] : hpk[i0];
            unsigned u0 = hh ? hpk[i0] : hpk[i0 + 2];
            unsigned w0 = __shfl_xor(u0, 32);
            unsigned A0 = hh ? w0 : t0;
            unsigned A2 = hh ? t0 : w0;
            unsigned t1 = hh ? hpk[i0 + 3] : hpk[i0 + 1];
            unsigned u1 = hh ? hpk[i0 + 1] : hpk[i0 + 3];
            unsigned w1 = __shfl_xor(u1, 32);
            unsigned A1 = hh ? w1 : t1;
            unsigned A3 = hh ? t1 : w1;

            unsigned s0 = hh ? lpk[i0 + 2] : lpk[i0];
            unsigned v0 = hh ? lpk[i0] : lpk[i0 + 2];
            unsigned x0 = __shfl_xor(v0, 32);
            unsigned B0 = hh ? x0 : s0;
            unsigned B2 = hh ? s0 : x0;
            unsigned s1 = hh ? lpk[i0 + 3] : lpk[i0 + 1];
            unsigned v1 = hh ? lpk[i0 + 1] : lpk[i0 + 3];
            unsigned x1 = __shfl_xor(v1, 32);
            unsigned B1 = hh ? x1 : s1;
            unsigned B3 = hh ? s1 : x1;

            bf16x8 pa_hi = u4_to_b8(make_uint4(A0, A1, A2, A3));
            bf16x8 pa_lo = u4_to_b8(make_uint4(B0, B1, B2, B3));
#pragma unroll
            for (int et = 0; et < 4; ++et) {
                bf16x8 vh = *(const bf16x8*)(Bp + (32 + (ks * 2 + 0) * 4 + et) * 1024 + lane * 16);
                bf16x8 vl = *(const bf16x8*)(Bp + (32 + (ks * 2 + 1) * 4 + et) * 1024 + lane * 16);
                O[et] = MFMA32(pa_hi, vh, O[et]);
                O[et] = MFMA32(pa_hi, vl, O[et]);
                O[et] = MFMA32(pa_lo, vh, O[et]);
            }
        }
        __syncthreads();
    }

    size_t ob = ((size_t)(split * S_ + s) * HW_ + qt * 128 + wv * 32) * CE_;
#pragma unroll
    for (int r = 0; r < 16; ++r) {
        int qrow = (r & 3) + 8 * (r >> 2) + (hh ? 4 : 0);
#pragma unroll
        for (int et = 0; et < 4; ++et)
            Opart[ob + (size_t)qrow * CE_ + et * 32 + l31] = O[et][r];
    }
    if (lane < 32) {
        size_t mb = (size_t)(split * S_ + s) * HW_ + qt * 128 + wv * 32 + lane;
        mpart[mb] = m;
        lpart[mb] = lsum;
    }
}

// ============================================================================
// Merge NSPLIT partials; out[s][e][q] layout (1,S,ce,h,w)
// ============================================================================
__global__ __launch_bounds__(128)
void cross_combine_kernel(const float* __restrict__ Opart, const float* __restrict__ mpart,
                          const float* __restrict__ lpart, float* __restrict__ out)
{
    const int s = blockIdx.x >> 10;
    const int q = blockIdx.x & 1023;
    const int e = threadIdx.x;
    float m[NSPLIT];
    float M = NEGINF;
#pragma unroll
    for (int i = 0; i < NSPLIT; ++i) {
        m[i] = mpart[(size_t)(i * S_ + s) * HW_ + q];
        M = fmaxf(M, m[i]);
    }
    float L = 0.f, v = 0.f;
#pragma unroll
    for (int i = 0; i < NSPLIT; ++i) {
        float w = expf(m[i] - M);
        L += w * lpart[(size_t)(i * S_ + s) * HW_ + q];
        v += w * Opart[((size_t)(i * S_ + s) * HW_ + q) * CE_ + e];
    }
    out[((size_t)s * CE_ + e) * HW_ + q] = v / L;
}

// ============================================================================
extern "C" void kernel_launch(void* const* d_in, const int* in_sizes, int n_in,
                              void* d_out, int out_size, void* d_ws, size_t ws_size,
                              hipStream_t stream) {
    (void)in_sizes; (void)n_in; (void)out_size; (void)ws_size;
    const float* tgt    = (const float*)d_in[0];
    const float* memory = (const float*)d_in[1];
    const float* pe     = (const float*)d_in[2];
    const float* wsw    = (const float*)d_in[3];
    const float* wsb    = (const float*)d_in[4];
    const float* wcw    = (const float*)d_in[5];
    const float* wcb    = (const float*)d_in[6];
    float* out = (float*)d_out;
    float* W = (float*)d_ws;
    char*  PFT   = (char*)(W + O_PFT);
    char*  XV    = (char*)(W + O_XV);
    float* Z     = W + O_Z;
    float* Zn    = W + O_ZN;
    char*  QFc   = (char*)(W + O_QF);
    char*  KFc   = (char*)(W + O_KF);
    char*  VFc   = (char*)(W + O_VF);
    float* Opart = W + O_OPART;   // overlays PFT/XV/Z (dead before cross_flash)
    float* mpart = W + O_MPART;
    float* lpart = W + O_LPART;

    // self path (fused MFMA flash)
    proj_frag_kernel<<<dim3(16, 4), 256, 0, stream>>>(tgt, wsw, wsb, PFT, HW_, SQRT30);
    xconv_kernel<<<dim3(512), 256, 0, stream>>>(tgt, XV);
    self_flash_mfma<<<dim3(8, 2, 4), 256, 0, stream>>>(PFT, XV, tgt, Z);
    inorm_kernel<<<dim3(S_ * C_), 256, 0, stream>>>(Z, Zn);
    // cross path
    proj_frag_kernel<<<dim3(16, 4), 256, 0, stream>>>(Zn, wcw, wcb, QFc, HW_, 30.0f);
    proj_frag_kernel<<<dim3(128, 4), 256, 0, stream>>>(memory, wcw, wcb, KFc, M_, 1.0f);
    vconv_kernel<<<dim3(2048), 256, 0, stream>>>(pe, VFc);
    cross_flash_mfma<<<dim3(8, NSPLIT, 4), 256, 0, stream>>>(QFc, KFc, VFc, Opart, mpart, lpart);
    cross_combine_kernel<<<dim3(S_ * HW_), 128, 0, stream>>>(Opart, mpart, lpart, out);
}

// Round 6
// 351.710 us; speedup vs baseline: 1.2677x; 1.2677x over previous
//
#include <hip/hip_runtime.h>

#define S_ 4
#define C_ 256
#define CE_ 128
#define KD_ 128
#define HW_ 1024
#define T_ 8
#define M_ 8192
#define NSPLIT 8
#define KSPLIT 1024          // M_ / NSPLIT
#define KTILES 16            // KSPLIT / 64
#define NEGINF -3.0e38f
#define LOG2E 1.4426950408889634f
#define SQRT30 5.4772255750516612f

typedef short bf16x8 __attribute__((ext_vector_type(8)));
typedef float f32x16 __attribute__((ext_vector_type(16)));

#define MFMA32(a, b, c) __builtin_amdgcn_mfma_f32_32x32x16_bf16(a, b, c, 0, 0, 0)

// ---------------- workspace layout (float offsets) ----------------
// live through self+proj phase:
//   PFT 0        (524288)   dead after self_flash
//   XV  524288   (1048576)  dead after self_flash
//   Z   1572864  (1048576)  dead after inorm
//   ZN  2621440  (1048576)  dead after proj_frag(Zn)
//   QF  3670016  (524288)   live into cross_flash
//   KF  4194304  (4194304)  live into cross_flash
//   VF  8388608  (4194304)  live into cross_flash
// total 12582912 floats = 50.3 MB
// cross-phase overlays (PFT/XV/Z dead before cross_flash writes):
//   OPART 0        u32[32][512][128] bf16-pairs = 2097152 slots
//   MPART 2097152  (NSPLIT*S*HW = 32768)
//   LPART 2129920  (32768) -> ends 2162688 < 2621440 (inside dead region) OK
#define O_PFT   0u
#define O_XV    524288u
#define O_Z     1572864u
#define O_ZN    2621440u
#define O_QF    3670016u
#define O_KF    4194304u
#define O_VF    8388608u
#define O_OPART 0u
#define O_MPART 2097152u
#define O_LPART 2129920u

__device__ __forceinline__ bf16x8 u4_to_b8(uint4 u) {
    union { uint4 u; bf16x8 b; } c; c.u = u; return c.b;
}

__device__ __forceinline__ unsigned cvt_pk_bf16(float a, float b) {
    unsigned r;
    asm("v_cvt_pk_bf16_f32 %0, %1, %2" : "=v"(r) : "v"(a), "v"(b));
    return r;
}

// ============================================================================
// GEMM + bias + l2norm -> hi/lo bf16 MFMA fragment granules:
// [s][rb32][hilo][dstep8][lane64*16B]. Element (r,d): lane=(r&31)|(((d>>3)&1)<<5),
// byte=(d&7)*2.
// ============================================================================
__global__ __launch_bounds__(256)
void proj_frag_kernel(const float* __restrict__ src, const float* __restrict__ Wm,
                      const float* __restrict__ bias, char* __restrict__ outF,
                      int R, float scale)
{
    __shared__ float Xs[32][65];
    __shared__ float Ws[32][129];
    const int s  = blockIdx.y;
    const int r0 = blockIdx.x * 64;
    const int t  = r0 >> 10;
    const int l0 = r0 & 1023;
    const int tid = threadIdx.x;
    const int tx = tid & 15, ty = tid >> 4;
    const float* xb = src + ((size_t)(t * S_ + s) * C_) * HW_ + l0;

    float acc[4][8];
#pragma unroll
    for (int i = 0; i < 4; ++i)
#pragma unroll
        for (int j = 0; j < 8; ++j) acc[i][j] = 0.f;

    for (int c0 = 0; c0 < C_; c0 += 32) {
#pragma unroll
        for (int j = 0; j < 8; ++j) {
            int idx = tid + j * 256;
            Xs[idx >> 6][idx & 63] = xb[(size_t)(c0 + (idx >> 6)) * HW_ + (idx & 63)];
        }
#pragma unroll
        for (int j = 0; j < 16; ++j) {
            int idx = tid + j * 256;
            Ws[idx & 31][idx >> 5] = Wm[(idx >> 5) * C_ + c0 + (idx & 31)];
        }
        __syncthreads();
        for (int cc = 0; cc < 32; ++cc) {
            float xv[4], wv[8];
#pragma unroll
            for (int i = 0; i < 4; ++i) xv[i] = Xs[cc][ty * 4 + i];
#pragma unroll
            for (int j = 0; j < 8; ++j) wv[j] = Ws[cc][tx * 8 + j];
#pragma unroll
            for (int i = 0; i < 4; ++i)
#pragma unroll
                for (int j = 0; j < 8; ++j) acc[i][j] = fmaf(xv[i], wv[j], acc[i][j]);
        }
        __syncthreads();
    }

    float bv[8];
#pragma unroll
    for (int j = 0; j < 8; ++j) bv[j] = bias[tx * 8 + j];

    const int RB = R >> 5;
#pragma unroll
    for (int i = 0; i < 4; ++i) {
        float ss = 0.f;
#pragma unroll
        for (int j = 0; j < 8; ++j) {
            acc[i][j] += bv[j];
            ss = fmaf(acc[i][j], acc[i][j], ss);
        }
#pragma unroll
        for (int m = 1; m < 16; m <<= 1) ss += __shfl_xor(ss, m);
        float sc = scale / fmaxf(sqrtf(ss), 1e-12f);
        int r = r0 + ty * 4 + i;
        float v[8];
#pragma unroll
        for (int j = 0; j < 8; ++j) v[j] = acc[i][j] * sc;
        unsigned hp[4], lp[4];
#pragma unroll
        for (int p = 0; p < 4; ++p) {
            hp[p] = cvt_pk_bf16(v[2 * p], v[2 * p + 1]);
            float f0 = __uint_as_float(hp[p] << 16);
            float f1 = __uint_as_float(hp[p] & 0xffff0000u);
            lp[p] = cvt_pk_bf16(v[2 * p] - f0, v[2 * p + 1] - f1);
        }
        int lane = (r & 31) | ((tx & 1) << 5);
        int ds = tx >> 1;
        size_t gb = ((((size_t)s * RB + (r >> 5)) * 2 + 0) * 8 + ds) * 1024 + (size_t)lane * 16;
        *(uint4*)(outF + gb) = make_uint4(hp[0], hp[1], hp[2], hp[3]);
        *(uint4*)(outF + gb + 8 * 1024) = make_uint4(lp[0], lp[1], lp[2], lp[3]);
    }
}

// ============================================================================
// pe -> cross-V granules [s][kb16][hilo][etile4][1KB]; hi HALF ONLY (PV hi-only)
// ============================================================================
__global__ __launch_bounds__(256)
void vconv_kernel(const float* __restrict__ pe, char* __restrict__ VF)
{
    int gid = blockIdx.x * 256 + threadIdx.x;   // 2^19 threads
    int lg = gid & 127;
    int e  = (gid >> 7) & 127;
    int s  = (gid >> 14) & 3;
    int t  = gid >> 16;
    int l0 = lg * 8;
    const float* p = pe + (((size_t)(t * S_ + s) * CE_ + e) * HW_ + l0);
    float4 va = ((const float4*)p)[0];
    float4 vb = ((const float4*)p)[1];
    unsigned hp[4];
    hp[0] = cvt_pk_bf16(va.x, va.y);
    hp[1] = cvt_pk_bf16(va.z, va.w);
    hp[2] = cvt_pk_bf16(vb.x, vb.y);
    hp[3] = cvt_pk_bf16(vb.z, vb.w);
    int k = t * 1024 + l0;
    int kb16 = k >> 4;
    int lane = (e & 31) | (((l0 >> 3) & 1) << 5);
    int et = e >> 5;
    size_t gb = ((((size_t)s * 512 + kb16) * 2 + 0) * 4 + et) * 1024 + (size_t)lane * 16;
    *(uint4*)(VF + gb) = make_uint4(hp[0], hp[1], hp[2], hp[3]);
}

// ============================================================================
// tgt -> self-V channel granules [s][kb16 64][hilo][cht8][1KB]; hi HALF ONLY
// ============================================================================
__global__ __launch_bounds__(256)
void xconv_kernel(const float* __restrict__ X, char* __restrict__ XV)
{
    int gid = blockIdx.x * 256 + threadIdx.x;   // 131072 threads
    int lg = gid & 127;
    int ch = (gid >> 7) & 255;
    int s  = gid >> 15;
    int l0 = lg * 8;
    const float* p = X + (((size_t)s * C_ + ch) * HW_ + l0);
    float4 va = ((const float4*)p)[0];
    float4 vb = ((const float4*)p)[1];
    unsigned hp[4];
    hp[0] = cvt_pk_bf16(va.x, va.y);
    hp[1] = cvt_pk_bf16(va.z, va.w);
    hp[2] = cvt_pk_bf16(vb.x, vb.y);
    hp[3] = cvt_pk_bf16(vb.z, vb.w);
    int kb16 = l0 >> 4;
    int lane = (ch & 31) | (((l0 >> 3) & 1) << 5);
    int cht = ch >> 5;
    size_t gb = ((((size_t)s * 64 + kb16) * 2 + 0) * 8 + cht) * 1024 + (size_t)lane * 16;
    *(uint4*)(XV + gb) = make_uint4(hp[0], hp[1], hp[2], hp[3]);
}

// ============================================================================
// Fused MFMA flash SELF-attention + residual. cs in 0..3: 64-ch slice.
// Grid 1D 128: g=bid&15 -> (cs=g>>2, s=g&3), qt=bid>>4 (XCD co-location: all
// qt-blocks of one (cs,s) share the same XCD via i%8 round-robin).
// LDS 2 x 40KB (K-P 32KB + XV-hi 8KB per tile), double-buffered.
// ============================================================================
__global__ __launch_bounds__(256, 1)
void self_flash_mfma(const char* __restrict__ PF, const char* __restrict__ XV,
                     const float* __restrict__ X, float* __restrict__ Z)
{
    __shared__ __align__(16) char lds[2][40960];
    const int bid = blockIdx.x;
    const int g = bid & 15;
    const int qt = bid >> 4;
    const int cs = g >> 2, s = g & 3;
    const int tid = threadIdx.x;
    const int wv = tid >> 6, lane = tid & 63;
    const int l31 = lane & 31;
    const bool hh = lane >= 32;
    const int qb32 = qt * 4 + wv;

    uint4 QH[8], QL[8];
    {
        const char* qb = PF + (((size_t)s * 32 + qb32) * 2) * 8192;
#pragma unroll
        for (int ds = 0; ds < 8; ++ds) {
            QH[ds] = *(const uint4*)(qb + ds * 1024 + lane * 16);
            QL[ds] = *(const uint4*)(qb + 8192 + ds * 1024 + lane * 16);
        }
    }

    f32x16 O[2];
#pragma unroll
    for (int et = 0; et < 2; ++et)
#pragma unroll
        for (int i = 0; i < 16; ++i) O[et][i] = 0.f;
    float m = NEGINF, lsum = 0.f;

    auto STAGE = [&](int b, int kt) {
        int k0 = kt * 64;
#pragma unroll
        for (int i = 0; i < 10; ++i) {
            int gg = wv * 10 + i;
            const char* src;
            if (gg < 32) {
                int at = gg >> 4, hl = (gg >> 3) & 1, ds = gg & 7;
                src = PF + ((((size_t)s * 32 + (k0 >> 5) + at) * 2 + hl) * 8 + ds) * 1024
                         + (size_t)lane * 16;
            } else {
                int g2 = gg - 32, ks = g2 >> 1, et = g2 & 1;
                src = XV + ((((size_t)s * 64 + (k0 >> 4) + ks) * 2 + 0) * 8 + cs * 2 + et) * 1024
                         + (size_t)lane * 16;
            }
            char* dst = &lds[b][gg * 1024];
            __builtin_amdgcn_global_load_lds(
                (const __attribute__((address_space(1))) void*)src,
                (__attribute__((address_space(3))) void*)dst, 16, 0, 0);
        }
    };

    STAGE(0, 0);
    __syncthreads();

    for (int kt = 0; kt < 16; ++kt) {
        const int b = kt & 1;
        if (kt < 15) STAGE(b ^ 1, kt + 1);
        const char* Bp = lds[b];

        // ---- scores: D = K * Q^T (full 3-MFMA split-bf16) ----
        f32x16 a0, a1;
#pragma unroll
        for (int i = 0; i < 16; ++i) { a0[i] = 0.f; a1[i] = 0.f; }
#pragma unroll
        for (int ds = 0; ds < 8; ++ds) {
            bf16x8 kh0 = *(const bf16x8*)(Bp + (0 + ds) * 1024 + lane * 16);
            bf16x8 kl0 = *(const bf16x8*)(Bp + (8 + ds) * 1024 + lane * 16);
            bf16x8 kh1 = *(const bf16x8*)(Bp + (16 + ds) * 1024 + lane * 16);
            bf16x8 kl1 = *(const bf16x8*)(Bp + (24 + ds) * 1024 + lane * 16);
            bf16x8 qh = u4_to_b8(QH[ds]), ql = u4_to_b8(QL[ds]);
            a0 = MFMA32(kh0, qh, a0);
            a0 = MFMA32(kh0, ql, a0);
            a0 = MFMA32(kl0, qh, a0);
            a1 = MFMA32(kh1, qh, a1);
            a1 = MFMA32(kh1, ql, a1);
            a1 = MFMA32(kl1, qh, a1);
        }

        // ---- online softmax (q = lane&31, lane-local) ----
        float tmax = NEGINF;
#pragma unroll
        for (int i = 0; i < 16; ++i) tmax = fmaxf(tmax, fmaxf(a0[i], a1[i]));
        tmax = fmaxf(tmax, __shfl_xor(tmax, 32));
        float mnew = fmaxf(m, tmax);
        float alpha = exp2f((m - mnew) * LOG2E);
        float mn2 = mnew * LOG2E;
        float P[32];
        float tsum = 0.f;
#pragma unroll
        for (int i = 0; i < 16; ++i) { P[i] = exp2f(fmaf(a0[i], LOG2E, -mn2)); tsum += P[i]; }
#pragma unroll
        for (int i = 0; i < 16; ++i) { P[16 + i] = exp2f(fmaf(a1[i], LOG2E, -mn2)); tsum += P[16 + i]; }
        tsum += __shfl_xor(tsum, 32);
        lsum = lsum * alpha + tsum;
        m = mnew;

#pragma unroll
        for (int et = 0; et < 2; ++et)
#pragma unroll
            for (int i = 0; i < 16; ++i) O[et][i] *= alpha;

        // ---- pack P hi only ----
        unsigned hpk[16];
#pragma unroll
        for (int p = 0; p < 16; ++p) hpk[p] = cvt_pk_bf16(P[2 * p], P[2 * p + 1]);

        // ---- PV (hi-only): O[ch][q] += X[ch][k] * P[k][q] ----
#pragma unroll
        for (int ks = 0; ks < 4; ++ks) {
            const int i0 = (ks >> 1) * 8 + (ks & 1) * 4;
            unsigned t0 = hh ? hpk[i0 + 2] : hpk[i0];
            unsigned u0 = hh ? hpk[i0] : hpk[i0 + 2];
            unsigned w0 = __shfl_xor(u0, 32);
            unsigned A0 = hh ? w0 : t0;
            unsigned A2 = hh ? t0 : w0;
            unsigned t1 = hh ? hpk[i0 + 3] : hpk[i0 + 1];
            unsigned u1 = hh ? hpk[i0 + 1] : hpk[i0 + 3];
            unsigned w1 = __shfl_xor(u1, 32);
            unsigned A1 = hh ? w1 : t1;
            unsigned A3 = hh ? t1 : w1;

            bf16x8 pa_hi = u4_to_b8(make_uint4(A0, A1, A2, A3));
#pragma unroll
            for (int et = 0; et < 2; ++et) {
                bf16x8 xh = *(const bf16x8*)(Bp + (32 + ks * 2 + et) * 1024 + lane * 16);
                O[et] = MFMA32(xh, pa_hi, O[et]);
            }
        }
        __syncthreads();
    }

    // ---- epilogue: normalize (lane-local), residual, coalesced (s,ch,q) ----
    float inv = 1.f / lsum;
    int q = qb32 * 32 + l31;
#pragma unroll
    for (int et = 0; et < 2; ++et)
#pragma unroll
        for (int r = 0; r < 16; ++r) {
            int ch = cs * 64 + et * 32 + (r & 3) + 8 * (r >> 2) + (hh ? 4 : 0);
            size_t a = ((size_t)s * C_ + ch) * HW_ + q;
            Z[a] = O[et][r] * inv + X[a];
        }
}

// ============================================================================
// InstanceNorm over spatial (1024) per (s,ch)
// ============================================================================
__global__ __launch_bounds__(256)
void inorm_kernel(const float* __restrict__ Z, float* __restrict__ Zn)
{
    __shared__ float red[4];
    __shared__ float red2[4];
    const float* p = Z + (size_t)blockIdx.x * HW_;
    float* q = Zn + (size_t)blockIdx.x * HW_;
    const int tid = threadIdx.x;
    float4 x = ((const float4*)p)[tid];
    float sm = x.x + x.y + x.z + x.w;
#pragma unroll
    for (int m = 1; m < 64; m <<= 1) sm += __shfl_xor(sm, m);
    if ((tid & 63) == 0) red[tid >> 6] = sm;
    __syncthreads();
    float mu = (red[0] + red[1] + red[2] + red[3]) * (1.f / 1024.f);
    float dx0 = x.x - mu, dx1 = x.y - mu, dx2 = x.z - mu, dx3 = x.w - mu;
    float ss = dx0 * dx0 + dx1 * dx1 + dx2 * dx2 + dx3 * dx3;
#pragma unroll
    for (int m = 1; m < 64; m <<= 1) ss += __shfl_xor(ss, m);
    if ((tid & 63) == 0) red2[tid >> 6] = ss;
    __syncthreads();
    float var = (red2[0] + red2[1] + red2[2] + red2[3]) * (1.f / 1024.f);
    float inv = 1.f / sqrtf(var + 1e-5f);
    float4 o;
    o.x = dx0 * inv; o.y = dx1 * inv; o.z = dx2 * inv; o.w = dx3 * inv;
    ((float4*)q)[tid] = o;
}

// ============================================================================
// MFMA flash CROSS-attention. NSPLIT=8: 1024 keys = 16 k-tiles per split.
// Grid 1D 256: g=bid&31 -> (split=g>>2, s=g&3), qt=bid>>5 (XCD co-location).
// PV hi-only; LDS 2 x 48KB. O partials packed bf16 (u32 [g][q/2][e]).
// ============================================================================
__global__ __launch_bounds__(256, 1)
void cross_flash_mfma(const char* __restrict__ QF, const char* __restrict__ KF,
                      const char* __restrict__ VF, unsigned* __restrict__ Opart,
                      float* __restrict__ mpart, float* __restrict__ lpart)
{
    __shared__ __align__(16) char lds[2][49152];
    const int bid = blockIdx.x;
    const int g = bid & 31;
    const int qt = bid >> 5;
    const int split = g >> 2, s = g & 3;
    const int tid = threadIdx.x;
    const int wv = tid >> 6, lane = tid & 63;
    const int l31 = lane & 31;
    const bool hh = lane >= 32;
    const int qb32 = qt * 4 + wv;

    uint4 QH[8], QL[8];
    {
        const char* qb = QF + (((size_t)s * 32 + qb32) * 2) * 8192;
#pragma unroll
        for (int ds = 0; ds < 8; ++ds) {
            QH[ds] = *(const uint4*)(qb + ds * 1024 + lane * 16);
            QL[ds] = *(const uint4*)(qb + 8192 + ds * 1024 + lane * 16);
        }
    }

    f32x16 O[4];
#pragma unroll
    for (int et = 0; et < 4; ++et)
#pragma unroll
        for (int i = 0; i < 16; ++i) O[et][i] = 0.f;
    float m = NEGINF, lsum = 0.f;

    const int k0base = split * KSPLIT;

    auto STAGE = [&](int b, int kt) {
        int k0 = k0base + kt * 64;
#pragma unroll
        for (int i = 0; i < 12; ++i) {
            int gg = wv * 12 + i;
            const char* src;
            if (gg < 32) {
                int at = gg >> 4, hl = (gg >> 3) & 1, ds = gg & 7;
                src = KF + ((((size_t)s * 256 + (k0 >> 5) + at) * 2 + hl) * 8 + ds) * 1024
                         + (size_t)lane * 16;
            } else {
                int g2 = gg - 32, ks = g2 >> 2, et = g2 & 3;
                src = VF + ((((size_t)s * 512 + (k0 >> 4) + ks) * 2 + 0) * 4 + et) * 1024
                         + (size_t)lane * 16;
            }
            char* dst = &lds[b][gg * 1024];
            __builtin_amdgcn_global_load_lds(
                (const __attribute__((address_space(1))) void*)src,
                (__attribute__((address_space(3))) void*)dst, 16, 0, 0);
        }
    };

    STAGE(0, 0);
    __syncthreads();

    for (int kt = 0; kt < KTILES; ++kt) {
        const int b = kt & 1;
        if (kt < KTILES - 1) STAGE(b ^ 1, kt + 1);
        const char* Bp = lds[b];

        f32x16 a0, a1;
#pragma unroll
        for (int i = 0; i < 16; ++i) { a0[i] = 0.f; a1[i] = 0.f; }
#pragma unroll
        for (int ds = 0; ds < 8; ++ds) {
            bf16x8 kh0 = *(const bf16x8*)(Bp + (0 + ds) * 1024 + lane * 16);
            bf16x8 kl0 = *(const bf16x8*)(Bp + (8 + ds) * 1024 + lane * 16);
            bf16x8 kh1 = *(const bf16x8*)(Bp + (16 + ds) * 1024 + lane * 16);
            bf16x8 kl1 = *(const bf16x8*)(Bp + (24 + ds) * 1024 + lane * 16);
            bf16x8 qh = u4_to_b8(QH[ds]), ql = u4_to_b8(QL[ds]);
            a0 = MFMA32(kh0, qh, a0);
            a0 = MFMA32(kh0, ql, a0);
            a0 = MFMA32(kl0, qh, a0);
            a1 = MFMA32(kh1, qh, a1);
            a1 = MFMA32(kh1, ql, a1);
            a1 = MFMA32(kl1, qh, a1);
        }

        float tmax = NEGINF;
#pragma unroll
        for (int i = 0; i < 16; ++i) tmax = fmaxf(tmax, fmaxf(a0[i], a1[i]));
        tmax = fmaxf(tmax, __shfl_xor(tmax, 32));
        float mnew = fmaxf(m, tmax);
        float alpha = exp2f((m - mnew) * LOG2E);
        float mn2 = mnew * LOG2E;
        float P[32];
        float tsum = 0.f;
#pragma unroll
        for (int i = 0; i < 16; ++i) { P[i] = exp2f(fmaf(a0[i], LOG2E, -mn2)); tsum += P[i]; }
#pragma unroll
        for (int i = 0; i < 16; ++i) { P[16 + i] = exp2f(fmaf(a1[i], LOG2E, -mn2)); tsum += P[16 + i]; }
        tsum += __shfl_xor(tsum, 32);
        lsum = lsum * alpha + tsum;
        m = mnew;

#pragma unroll
        for (int r = 0; r < 16; ++r) {
            int qrow = (r & 3) + 8 * (r >> 2) + (hh ? 4 : 0);
            float ar = __shfl(alpha, qrow | (hh ? 32 : 0));
#pragma unroll
            for (int et = 0; et < 4; ++et) O[et][r] *= ar;
        }

        unsigned hpk[16];
#pragma unroll
        for (int p = 0; p < 16; ++p) hpk[p] = cvt_pk_bf16(P[2 * p], P[2 * p + 1]);

        // ---- PV (hi-only): O[q][e] += P[q][k] * V[k][e] ----
#pragma unroll
        for (int ks = 0; ks < 4; ++ks) {
            const int i0 = (ks >> 1) * 8 + (ks & 1) * 4;
            unsigned t0 = hh ? hpk[i0 + 2] : hpk[i0];
            unsigned u0 = hh ? hpk[i0] : hpk[i0 + 2];
            unsigned w0 = __shfl_xor(u0, 32);
            unsigned A0 = hh ? w0 : t0;
            unsigned A2 = hh ? t0 : w0;
            unsigned t1 = hh ? hpk[i0 + 3] : hpk[i0 + 1];
            unsigned u1 = hh ? hpk[i0 + 1] : hpk[i0 + 3];
            unsigned w1 = __shfl_xor(u1, 32);
            unsigned A1 = hh ? w1 : t1;
            unsigned A3 = hh ? t1 : w1;

            bf16x8 pa_hi = u4_to_b8(make_uint4(A0, A1, A2, A3));
#pragma unroll
            for (int et = 0; et < 4; ++et) {
                bf16x8 vh = *(const bf16x8*)(Bp + (32 + ks * 4 + et) * 1024 + lane * 16);
                O[et] = MFMA32(pa_hi, vh, O[et]);
            }
        }
        __syncthreads();
    }

    // ---- epilogue: bf16-pair partials [g][q/2][e], coalesced over e ----
    size_t gbase = (size_t)(split * S_ + s) * 512 * 128;
#pragma unroll
    for (int et = 0; et < 4; ++et) {
        int e = et * 32 + l31;
#pragma unroll
        for (int p = 0; p < 8; ++p) {
            int r = 2 * p;
            int qrow = (r & 3) + 8 * (r >> 2) + (hh ? 4 : 0);
            unsigned pk = cvt_pk_bf16(O[et][r], O[et][r + 1]);
            int qh2 = (qt * 128 + wv * 32 + qrow) >> 1;
            Opart[gbase + (size_t)qh2 * 128 + e] = pk;
        }
    }
    if (lane < 32) {
        size_t mb = (size_t)(split * S_ + s) * HW_ + qt * 128 + wv * 32 + lane;
        mpart[mb] = m;
        lpart[mb] = lsum;
    }
}

// ============================================================================
// Merge NSPLIT bf16-pair partials; out[s][e][q]. Block=(s,e), threads=q/4:
// coalesced float4 output rows.
// ============================================================================
__global__ __launch_bounds__(256)
void cross_combine_kernel(const unsigned* __restrict__ Opart, const float* __restrict__ mpart,
                          const float* __restrict__ lpart, float* __restrict__ out)
{
    const int s = blockIdx.x >> 7;
    const int e = blockIdx.x & 127;
    const int q0 = threadIdx.x * 4;

    float mm[NSPLIT][4];
    float M[4] = {NEGINF, NEGINF, NEGINF, NEGINF};
#pragma unroll
    for (int i = 0; i < NSPLIT; ++i) {
        float4 m4 = *(const float4*)&mpart[(size_t)(i * S_ + s) * HW_ + q0];
        mm[i][0] = m4.x; mm[i][1] = m4.y; mm[i][2] = m4.z; mm[i][3] = m4.w;
#pragma unroll
        for (int j = 0; j < 4; ++j) M[j] = fmaxf(M[j], mm[i][j]);
    }
    float L[4] = {0.f, 0.f, 0.f, 0.f};
    float acc[4] = {0.f, 0.f, 0.f, 0.f};
#pragma unroll
    for (int i = 0; i < NSPLIT; ++i) {
        float4 l4 = *(const float4*)&lpart[(size_t)(i * S_ + s) * HW_ + q0];
        float w0 = expf(mm[i][0] - M[0]);
        float w1 = expf(mm[i][1] - M[1]);
        float w2 = expf(mm[i][2] - M[2]);
        float w3 = expf(mm[i][3] - M[3]);
        L[0] += w0 * l4.x; L[1] += w1 * l4.y; L[2] += w2 * l4.z; L[3] += w3 * l4.w;
        size_t ob = (size_t)(i * S_ + s) * 512 * 128;
        unsigned pa = Opart[ob + (size_t)(q0 >> 1) * 128 + e];
        unsigned pb = Opart[ob + (size_t)((q0 >> 1) + 1) * 128 + e];
        acc[0] += w0 * __uint_as_float(pa << 16);
        acc[1] += w1 * __uint_as_float(pa & 0xffff0000u);
        acc[2] += w2 * __uint_as_float(pb << 16);
        acc[3] += w3 * __uint_as_float(pb & 0xffff0000u);
    }
    float4 o;
    o.x = acc[0] / L[0]; o.y = acc[1] / L[1]; o.z = acc[2] / L[2]; o.w = acc[3] / L[3];
    *(float4*)&out[((size_t)s * CE_ + e) * HW_ + q0] = o;
}

// ============================================================================
extern "C" void kernel_launch(void* const* d_in, const int* in_sizes, int n_in,
                              void* d_out, int out_size, void* d_ws, size_t ws_size,
                              hipStream_t stream) {
    (void)in_sizes; (void)n_in; (void)out_size; (void)ws_size;
    const float* tgt    = (const float*)d_in[0];
    const float* memory = (const float*)d_in[1];
    const float* pe     = (const float*)d_in[2];
    const float* wsw    = (const float*)d_in[3];
    const float* wsb    = (const float*)d_in[4];
    const float* wcw    = (const float*)d_in[5];
    const float* wcb    = (const float*)d_in[6];
    float* out = (float*)d_out;
    float* W = (float*)d_ws;
    char*  PFT   = (char*)(W + O_PFT);
    char*  XV    = (char*)(W + O_XV);
    float* Z     = W + O_Z;
    float* Zn    = W + O_ZN;
    char*  QFc   = (char*)(W + O_QF);
    char*  KFc   = (char*)(W + O_KF);
    char*  VFc   = (char*)(W + O_VF);
    unsigned* Opart = (unsigned*)(W + O_OPART);  // overlays dead PFT/XV/Z
    float* mpart = W + O_MPART;
    float* lpart = W + O_LPART;

    // self path (fused MFMA flash)
    proj_frag_kernel<<<dim3(16, 4), 256, 0, stream>>>(tgt, wsw, wsb, PFT, HW_, SQRT30);
    xconv_kernel<<<dim3(512), 256, 0, stream>>>(tgt, XV);
    self_flash_mfma<<<dim3(128), 256, 0, stream>>>(PFT, XV, tgt, Z);
    inorm_kernel<<<dim3(S_ * C_), 256, 0, stream>>>(Z, Zn);
    // cross path
    proj_frag_kernel<<<dim3(16, 4), 256, 0, stream>>>(Zn, wcw, wcb, QFc, HW_, 30.0f);
    proj_frag_kernel<<<dim3(128, 4), 256, 0, stream>>>(memory, wcw, wcb, KFc, M_, 1.0f);
    vconv_kernel<<<dim3(2048), 256, 0, stream>>>(pe, VFc);
    cross_flash_mfma<<<dim3(256), 256, 0, stream>>>(QFc, KFc, VFc, Opart, mpart, lpart);
    cross_combine_kernel<<<dim3(S_ * CE_), 256, 0, stream>>>(Opart, mpart, lpart, out);
}

// Round 7
// 251.859 us; speedup vs baseline: 1.7702x; 1.3965x over previous
//
#include <hip/hip_runtime.h>

#define S_ 4
#define C_ 256
#define CE_ 128
#define KD_ 128
#define HW_ 1024
#define T_ 8
#define M_ 8192
#define NSPLIT 8
#define KSPLIT 1024          // M_ / NSPLIT
#define KTILES 16            // KSPLIT / 64
#define NEGINF -3.0e38f
#define LOG2E 1.4426950408889634f
#define SQRT30 5.4772255750516612f

typedef short bf16x8 __attribute__((ext_vector_type(8)));
typedef float f32x16 __attribute__((ext_vector_type(16)));

#define MFMA32(a, b, c) __builtin_amdgcn_mfma_f32_32x32x16_bf16(a, b, c, 0, 0, 0)

// ---------------- workspace layout (float offsets) ----------------
//   PFT 0        (524288)   dead after self_flash
//   XV  524288   (1048576)  dead after self_flash
//   Z   1572864  (1048576)  dead after inorm
//   ZN  2621440  (1048576)  dead after proj(Zn)
//   QF  3670016  (524288)   live into cross_flash
//   KF  4194304  (4194304)  live into cross_flash
//   VF  8388608  (4194304)  live into cross_flash
//   WSF 12582912 (33280)    self W frags + bias (132KB region)
//   WCF 12616192 (33280)    cross W frags + bias
// total 12649472 floats = 50.6 MB
// cross-phase overlays (PFT/XV/Z dead before cross_flash writes):
//   OPART 0        u32 bf16-pairs (2097152)
//   MPART 2097152  (32768)
//   LPART 2129920  (32768) -> ends 2162688 < 2621440 OK
#define O_PFT   0u
#define O_XV    524288u
#define O_Z     1572864u
#define O_ZN    2621440u
#define O_QF    3670016u
#define O_KF    4194304u
#define O_VF    8388608u
#define O_WSF   12582912u
#define O_WCF   12616192u
#define O_OPART 0u
#define O_MPART 2097152u
#define O_LPART 2129920u

__device__ __forceinline__ bf16x8 u4_to_b8(uint4 u) {
    union { uint4 u; bf16x8 b; } c; c.u = u; return c.b;
}

__device__ __forceinline__ unsigned cvt_pk_bf16(float a, float b) {
    unsigned r;
    asm("v_cvt_pk_bf16_f32 %0, %1, %2" : "=v"(r) : "v"(a), "v"(b));
    return r;
}

// ============================================================================
// W (128d x 256ch) + bias -> A-operand granules in ws.
// Granule g = (ks*2+hl)*4+dt (128 total, 1KB each): element (d, kk):
// lane=(d&31)|(((kk>>3)&1)<<5), byte=(kk&7)*2; d=dt*32+(lane&31),
// ch=ks*16+(lane>>5)*8+j. Bias copied to WF+131072 (512B).
// ============================================================================
__global__ __launch_bounds__(256)
void wconv_kernel(const float* __restrict__ Wm, const float* __restrict__ bias,
                  char* __restrict__ WF)
{
    if (blockIdx.x == 32) {
        if (threadIdx.x < 128)
            ((float*)(WF + 131072))[threadIdx.x] = bias[threadIdx.x];
        return;
    }
    int gid = blockIdx.x * 256 + threadIdx.x;   // 0..8191
    int lane = gid & 63;
    int g = gid >> 6;                            // 0..127
    int dt = g & 3, hl = (g >> 2) & 1, ks = g >> 3;
    int d = dt * 32 + (lane & 31);
    int ch = ks * 16 + (lane >> 5) * 8;
    const float* wp = Wm + (size_t)d * C_ + ch;
    float4 wa = *(const float4*)wp;
    float4 wb = *(const float4*)(wp + 4);
    float v[8] = {wa.x, wa.y, wa.z, wa.w, wb.x, wb.y, wb.z, wb.w};
    unsigned pk[4];
#pragma unroll
    for (int p = 0; p < 4; ++p) {
        unsigned hp = cvt_pk_bf16(v[2 * p], v[2 * p + 1]);
        if (hl == 0) pk[p] = hp;
        else {
            float f0 = __uint_as_float(hp << 16);
            float f1 = __uint_as_float(hp & 0xffff0000u);
            pk[p] = cvt_pk_bf16(v[2 * p] - f0, v[2 * p + 1] - f1);
        }
    }
    *(uint4*)(WF + (size_t)g * 1024 + lane * 16) = make_uint4(pk[0], pk[1], pk[2], pk[3]);
}

// ============================================================================
// MFMA projection: P = l2norm(X @ W^T + b) * scale -> hi/lo granules
// (identical output format to old proj_frag). Block = 128 rows (4 waves x 32r),
// K = 256 ch in 8 chunks of 32. A = W-frags (streamed from ws via
// global_load_lds), B = X-frags (fp32 staged linear, built in-reg per lane).
// D[d][r]: col=lane&31=r, row d=(reg&3)+8*(reg>>2)+4*(lane>>5) -> repacked to
// granules with the verified cvt_pk + shfl_xor(32) pattern.
// ============================================================================
__global__ __launch_bounds__(256, 1)
void proj_mfma_kernel(const float* __restrict__ src, const char* __restrict__ WF,
                      char* __restrict__ outF, int R, float scale)
{
    __shared__ __align__(16) char lds[2][32768];   // [0,16K): X fp32 [32ch][128r]; [16K,32K): W granules
    const int s  = blockIdx.y;
    const int r0 = blockIdx.x * 128;
    const int t  = r0 >> 10;
    const int l0 = r0 & 1023;
    const int tid = threadIdx.x;
    const int wv = tid >> 6, lane = tid & 63;
    const bool hh = lane >= 32;
    const int rl = wv * 32 + (lane & 31);          // block-local row

    const float* xb = src + ((size_t)(t * S_ + s) * C_) * HW_ + l0;

    f32x16 acc[4];
#pragma unroll
    for (int dt = 0; dt < 4; ++dt)
#pragma unroll
        for (int i = 0; i < 16; ++i) acc[dt][i] = 0.f;

    auto STAGE = [&](int b, int chunk) {
        // X fp32: 16 x 1KB calls (ch pair each), 4 per wave
#pragma unroll
        for (int i = 0; i < 4; ++i) {
            int c = wv * 4 + i;
            const float* sp = xb + (size_t)(chunk * 32 + 2 * c + (lane >> 5)) * HW_ + (lane & 31) * 4;
            char* dst = &lds[b][c * 1024];
            __builtin_amdgcn_global_load_lds(
                (const __attribute__((address_space(1))) void*)sp,
                (__attribute__((address_space(3))) void*)dst, 16, 0, 0);
        }
        // W granules: 16 x 1KB, 4 per wave
#pragma unroll
        for (int i = 0; i < 4; ++i) {
            int gi = wv * 4 + i;
            const char* sp = WF + (size_t)(chunk * 16 + gi) * 1024 + lane * 16;
            char* dst = &lds[b][16384 + gi * 1024];
            __builtin_amdgcn_global_load_lds(
                (const __attribute__((address_space(1))) void*)sp,
                (__attribute__((address_space(3))) void*)dst, 16, 0, 0);
        }
    };

    STAGE(0, 0);
    __syncthreads();

    for (int chunk = 0; chunk < 8; ++chunk) {
        const int b = chunk & 1;
        if (chunk < 7) STAGE(b ^ 1, chunk + 1);
        const float* Xs = (const float*)&lds[b][0];
        const char* Wg = &lds[b][16384];

#pragma unroll
        for (int ks = 0; ks < 2; ++ks) {
            int cb = ks * 16 + (lane >> 5) * 8;
            float v[8];
#pragma unroll
            for (int j = 0; j < 8; ++j) v[j] = Xs[(cb + j) * 128 + rl];
            unsigned bh[4], bl[4];
#pragma unroll
            for (int p = 0; p < 4; ++p) {
                bh[p] = cvt_pk_bf16(v[2 * p], v[2 * p + 1]);
                float f0 = __uint_as_float(bh[p] << 16);
                float f1 = __uint_as_float(bh[p] & 0xffff0000u);
                bl[p] = cvt_pk_bf16(v[2 * p] - f0, v[2 * p + 1] - f1);
            }
            bf16x8 Bh = u4_to_b8(make_uint4(bh[0], bh[1], bh[2], bh[3]));
            bf16x8 Bl = u4_to_b8(make_uint4(bl[0], bl[1], bl[2], bl[3]));
#pragma unroll
            for (int dt = 0; dt < 4; ++dt) {
                bf16x8 Ah = *(const bf16x8*)(Wg + (size_t)(((ks * 2 + 0) * 4 + dt) * 1024) + lane * 16);
                bf16x8 Al = *(const bf16x8*)(Wg + (size_t)(((ks * 2 + 1) * 4 + dt) * 1024) + lane * 16);
                acc[dt] = MFMA32(Ah, Bh, acc[dt]);
                acc[dt] = MFMA32(Ah, Bl, acc[dt]);
                acc[dt] = MFMA32(Al, Bh, acc[dt]);
            }
        }
        __syncthreads();
    }

    // ---- epilogue: +bias (fp32), l2norm over 128 d, scale, pack granules ----
    const float* bptr = (const float*)(WF + 131072);
    const int h4 = (lane >> 5) * 4;
    float ss = 0.f;
#pragma unroll
    for (int dt = 0; dt < 4; ++dt) {
#pragma unroll
        for (int g = 0; g < 4; ++g) {
            float4 bv = *(const float4*)(bptr + dt * 32 + g * 8 + h4);
            acc[dt][4 * g + 0] += bv.x;
            acc[dt][4 * g + 1] += bv.y;
            acc[dt][4 * g + 2] += bv.z;
            acc[dt][4 * g + 3] += bv.w;
        }
#pragma unroll
        for (int i = 0; i < 16; ++i) ss = fmaf(acc[dt][i], acc[dt][i], ss);
    }
    ss += __shfl_xor(ss, 32);
    float sc = scale / fmaxf(sqrtf(ss), 1e-12f);

    const int RB = R >> 5;
    const int rb = blockIdx.x * 4 + wv;
#pragma unroll
    for (int dt = 0; dt < 4; ++dt) {
        float vs[16];
#pragma unroll
        for (int i = 0; i < 16; ++i) vs[i] = acc[dt][i] * sc;
        unsigned hpk[8], lpk[8];
#pragma unroll
        for (int p = 0; p < 8; ++p) {
            hpk[p] = cvt_pk_bf16(vs[2 * p], vs[2 * p + 1]);
            float f0 = __uint_as_float(hpk[p] << 16);
            float f1 = __uint_as_float(hpk[p] & 0xffff0000u);
            lpk[p] = cvt_pk_bf16(vs[2 * p] - f0, vs[2 * p + 1] - f1);
        }
#pragma unroll
        for (int half = 0; half < 2; ++half) {
            const int i0 = half * 4;
            unsigned t0 = hh ? hpk[i0 + 2] : hpk[i0];
            unsigned u0 = hh ? hpk[i0] : hpk[i0 + 2];
            unsigned w0 = __shfl_xor(u0, 32);
            unsigned A0 = hh ? w0 : t0;
            unsigned A2 = hh ? t0 : w0;
            unsigned t1 = hh ? hpk[i0 + 3] : hpk[i0 + 1];
            unsigned u1 = hh ? hpk[i0 + 1] : hpk[i0 + 3];
            unsigned w1 = __shfl_xor(u1, 32);
            unsigned A1 = hh ? w1 : t1;
            unsigned A3 = hh ? t1 : w1;

            unsigned s0 = hh ? lpk[i0 + 2] : lpk[i0];
            unsigned v0 = hh ? lpk[i0] : lpk[i0 + 2];
            unsigned x0 = __shfl_xor(v0, 32);
            unsigned B0 = hh ? x0 : s0;
            unsigned B2 = hh ? s0 : x0;
            unsigned s1 = hh ? lpk[i0 + 3] : lpk[i0 + 1];
            unsigned v1 = hh ? lpk[i0 + 1] : lpk[i0 + 3];
            unsigned x1 = __shfl_xor(v1, 32);
            unsigned B1 = hh ? x1 : s1;
            unsigned B3 = hh ? s1 : x1;

            int ds = dt * 2 + half;
            size_t gb = ((((size_t)s * RB + rb) * 2 + 0) * 8 + ds) * 1024 + (size_t)lane * 16;
            *(uint4*)(outF + gb) = make_uint4(A0, A1, A2, A3);
            *(uint4*)(outF + gb + 8 * 1024) = make_uint4(B0, B1, B2, B3);
        }
    }
}

// ============================================================================
// pe -> cross-V granules [s][kb16][hilo][etile4][1KB]; hi HALF ONLY (PV hi-only)
// ============================================================================
__global__ __launch_bounds__(256)
void vconv_kernel(const float* __restrict__ pe, char* __restrict__ VF)
{
    int gid = blockIdx.x * 256 + threadIdx.x;   // 2^19 threads
    int lg = gid & 127;
    int e  = (gid >> 7) & 127;
    int s  = (gid >> 14) & 3;
    int t  = gid >> 16;
    int l0 = lg * 8;
    const float* p = pe + (((size_t)(t * S_ + s) * CE_ + e) * HW_ + l0);
    float4 va = ((const float4*)p)[0];
    float4 vb = ((const float4*)p)[1];
    unsigned hp[4];
    hp[0] = cvt_pk_bf16(va.x, va.y);
    hp[1] = cvt_pk_bf16(va.z, va.w);
    hp[2] = cvt_pk_bf16(vb.x, vb.y);
    hp[3] = cvt_pk_bf16(vb.z, vb.w);
    int k = t * 1024 + l0;
    int kb16 = k >> 4;
    int lane = (e & 31) | (((l0 >> 3) & 1) << 5);
    int et = e >> 5;
    size_t gb = ((((size_t)s * 512 + kb16) * 2 + 0) * 4 + et) * 1024 + (size_t)lane * 16;
    *(uint4*)(VF + gb) = make_uint4(hp[0], hp[1], hp[2], hp[3]);
}

// ============================================================================
// tgt -> self-V channel granules [s][kb16 64][hilo][cht8][1KB]; hi HALF ONLY
// ============================================================================
__global__ __launch_bounds__(256)
void xconv_kernel(const float* __restrict__ X, char* __restrict__ XV)
{
    int gid = blockIdx.x * 256 + threadIdx.x;   // 131072 threads
    int lg = gid & 127;
    int ch = (gid >> 7) & 255;
    int s  = gid >> 15;
    int l0 = lg * 8;
    const float* p = X + (((size_t)s * C_ + ch) * HW_ + l0);
    float4 va = ((const float4*)p)[0];
    float4 vb = ((const float4*)p)[1];
    unsigned hp[4];
    hp[0] = cvt_pk_bf16(va.x, va.y);
    hp[1] = cvt_pk_bf16(va.z, va.w);
    hp[2] = cvt_pk_bf16(vb.x, vb.y);
    hp[3] = cvt_pk_bf16(vb.z, vb.w);
    int kb16 = l0 >> 4;
    int lane = (ch & 31) | (((l0 >> 3) & 1) << 5);
    int cht = ch >> 5;
    size_t gb = ((((size_t)s * 64 + kb16) * 2 + 0) * 8 + cht) * 1024 + (size_t)lane * 16;
    *(uint4*)(XV + gb) = make_uint4(hp[0], hp[1], hp[2], hp[3]);
}

// ============================================================================
// Fused MFMA flash SELF-attention + residual (unchanged, verified round 6).
// ============================================================================
__global__ __launch_bounds__(256, 1)
void self_flash_mfma(const char* __restrict__ PF, const char* __restrict__ XV,
                     const float* __restrict__ X, float* __restrict__ Z)
{
    __shared__ __align__(16) char lds[2][40960];
    const int bid = blockIdx.x;
    const int g = bid & 15;
    const int qt = bid >> 4;
    const int cs = g >> 2, s = g & 3;
    const int tid = threadIdx.x;
    const int wv = tid >> 6, lane = tid & 63;
    const int l31 = lane & 31;
    const bool hh = lane >= 32;
    const int qb32 = qt * 4 + wv;

    uint4 QH[8], QL[8];
    {
        const char* qb = PF + (((size_t)s * 32 + qb32) * 2) * 8192;
#pragma unroll
        for (int ds = 0; ds < 8; ++ds) {
            QH[ds] = *(const uint4*)(qb + ds * 1024 + lane * 16);
            QL[ds] = *(const uint4*)(qb + 8192 + ds * 1024 + lane * 16);
        }
    }

    f32x16 O[2];
#pragma unroll
    for (int et = 0; et < 2; ++et)
#pragma unroll
        for (int i = 0; i < 16; ++i) O[et][i] = 0.f;
    float m = NEGINF, lsum = 0.f;

    auto STAGE = [&](int b, int kt) {
        int k0 = kt * 64;
#pragma unroll
        for (int i = 0; i < 10; ++i) {
            int gg = wv * 10 + i;
            const char* src;
            if (gg < 32) {
                int at = gg >> 4, hl = (gg >> 3) & 1, ds = gg & 7;
                src = PF + ((((size_t)s * 32 + (k0 >> 5) + at) * 2 + hl) * 8 + ds) * 1024
                         + (size_t)lane * 16;
            } else {
                int g2 = gg - 32, ks = g2 >> 1, et = g2 & 1;
                src = XV + ((((size_t)s * 64 + (k0 >> 4) + ks) * 2 + 0) * 8 + cs * 2 + et) * 1024
                         + (size_t)lane * 16;
            }
            char* dst = &lds[b][gg * 1024];
            __builtin_amdgcn_global_load_lds(
                (const __attribute__((address_space(1))) void*)src,
                (__attribute__((address_space(3))) void*)dst, 16, 0, 0);
        }
    };

    STAGE(0, 0);
    __syncthreads();

    for (int kt = 0; kt < 16; ++kt) {
        const int b = kt & 1;
        if (kt < 15) STAGE(b ^ 1, kt + 1);
        const char* Bp = lds[b];

        f32x16 a0, a1;
#pragma unroll
        for (int i = 0; i < 16; ++i) { a0[i] = 0.f; a1[i] = 0.f; }
#pragma unroll
        for (int ds = 0; ds < 8; ++ds) {
            bf16x8 kh0 = *(const bf16x8*)(Bp + (0 + ds) * 1024 + lane * 16);
            bf16x8 kl0 = *(const bf16x8*)(Bp + (8 + ds) * 1024 + lane * 16);
            bf16x8 kh1 = *(const bf16x8*)(Bp + (16 + ds) * 1024 + lane * 16);
            bf16x8 kl1 = *(const bf16x8*)(Bp + (24 + ds) * 1024 + lane * 16);
            bf16x8 qh = u4_to_b8(QH[ds]), ql = u4_to_b8(QL[ds]);
            a0 = MFMA32(kh0, qh, a0);
            a0 = MFMA32(kh0, ql, a0);
            a0 = MFMA32(kl0, qh, a0);
            a1 = MFMA32(kh1, qh, a1);
            a1 = MFMA32(kh1, ql, a1);
            a1 = MFMA32(kl1, qh, a1);
        }

        float tmax = NEGINF;
#pragma unroll
        for (int i = 0; i < 16; ++i) tmax = fmaxf(tmax, fmaxf(a0[i], a1[i]));
        tmax = fmaxf(tmax, __shfl_xor(tmax, 32));
        float mnew = fmaxf(m, tmax);
        float alpha = exp2f((m - mnew) * LOG2E);
        float mn2 = mnew * LOG2E;
        float P[32];
        float tsum = 0.f;
#pragma unroll
        for (int i = 0; i < 16; ++i) { P[i] = exp2f(fmaf(a0[i], LOG2E, -mn2)); tsum += P[i]; }
#pragma unroll
        for (int i = 0; i < 16; ++i) { P[16 + i] = exp2f(fmaf(a1[i], LOG2E, -mn2)); tsum += P[16 + i]; }
        tsum += __shfl_xor(tsum, 32);
        lsum = lsum * alpha + tsum;
        m = mnew;

#pragma unroll
        for (int et = 0; et < 2; ++et)
#pragma unroll
            for (int i = 0; i < 16; ++i) O[et][i] *= alpha;

        unsigned hpk[16];
#pragma unroll
        for (int p = 0; p < 16; ++p) hpk[p] = cvt_pk_bf16(P[2 * p], P[2 * p + 1]);

#pragma unroll
        for (int ks = 0; ks < 4; ++ks) {
            const int i0 = (ks >> 1) * 8 + (ks & 1) * 4;
            unsigned t0 = hh ? hpk[i0 + 2] : hpk[i0];
            unsigned u0 = hh ? hpk[i0] : hpk[i0 + 2];
            unsigned w0 = __shfl_xor(u0, 32);
            unsigned A0 = hh ? w0 : t0;
            unsigned A2 = hh ? t0 : w0;
            unsigned t1 = hh ? hpk[i0 + 3] : hpk[i0 + 1];
            unsigned u1 = hh ? hpk[i0 + 1] : hpk[i0 + 3];
            unsigned w1 = __shfl_xor(u1, 32);
            unsigned A1 = hh ? w1 : t1;
            unsigned A3 = hh ? t1 : w1;

            bf16x8 pa_hi = u4_to_b8(make_uint4(A0, A1, A2, A3));
#pragma unroll
            for (int et = 0; et < 2; ++et) {
                bf16x8 xh = *(const bf16x8*)(Bp + (32 + ks * 2 + et) * 1024 + lane * 16);
                O[et] = MFMA32(xh, pa_hi, O[et]);
            }
        }
        __syncthreads();
    }

    float inv = 1.f / lsum;
    int q = qb32 * 32 + l31;
#pragma unroll
    for (int et = 0; et < 2; ++et)
#pragma unroll
        for (int r = 0; r < 16; ++r) {
            int ch = cs * 64 + et * 32 + (r & 3) + 8 * (r >> 2) + (hh ? 4 : 0);
            size_t a = ((size_t)s * C_ + ch) * HW_ + q;
            Z[a] = O[et][r] * inv + X[a];
        }
}

// ============================================================================
// InstanceNorm over spatial (1024) per (s,ch)
// ============================================================================
__global__ __launch_bounds__(256)
void inorm_kernel(const float* __restrict__ Z, float* __restrict__ Zn)
{
    __shared__ float red[4];
    __shared__ float red2[4];
    const float* p = Z + (size_t)blockIdx.x * HW_;
    float* q = Zn + (size_t)blockIdx.x * HW_;
    const int tid = threadIdx.x;
    float4 x = ((const float4*)p)[tid];
    float sm = x.x + x.y + x.z + x.w;
#pragma unroll
    for (int m = 1; m < 64; m <<= 1) sm += __shfl_xor(sm, m);
    if ((tid & 63) == 0) red[tid >> 6] = sm;
    __syncthreads();
    float mu = (red[0] + red[1] + red[2] + red[3]) * (1.f / 1024.f);
    float dx0 = x.x - mu, dx1 = x.y - mu, dx2 = x.z - mu, dx3 = x.w - mu;
    float ss = dx0 * dx0 + dx1 * dx1 + dx2 * dx2 + dx3 * dx3;
#pragma unroll
    for (int m = 1; m < 64; m <<= 1) ss += __shfl_xor(ss, m);
    if ((tid & 63) == 0) red2[tid >> 6] = ss;
    __syncthreads();
    float var = (red2[0] + red2[1] + red2[2] + red2[3]) * (1.f / 1024.f);
    float inv = 1.f / sqrtf(var + 1e-5f);
    float4 o;
    o.x = dx0 * inv; o.y = dx1 * inv; o.z = dx2 * inv; o.w = dx3 * inv;
    ((float4*)q)[tid] = o;
}

// ============================================================================
// MFMA flash CROSS-attention (unchanged, verified round 6).
// ============================================================================
__global__ __launch_bounds__(256, 1)
void cross_flash_mfma(const char* __restrict__ QF, const char* __restrict__ KF,
                      const char* __restrict__ VF, unsigned* __restrict__ Opart,
                      float* __restrict__ mpart, float* __restrict__ lpart)
{
    __shared__ __align__(16) char lds[2][49152];
    const int bid = blockIdx.x;
    const int g = bid & 31;
    const int qt = bid >> 5;
    const int split = g >> 2, s = g & 3;
    const int tid = threadIdx.x;
    const int wv = tid >> 6, lane = tid & 63;
    const int l31 = lane & 31;
    const bool hh = lane >= 32;
    const int qb32 = qt * 4 + wv;

    uint4 QH[8], QL[8];
    {
        const char* qb = QF + (((size_t)s * 32 + qb32) * 2) * 8192;
#pragma unroll
        for (int ds = 0; ds < 8; ++ds) {
            QH[ds] = *(const uint4*)(qb + ds * 1024 + lane * 16);
            QL[ds] = *(const uint4*)(qb + 8192 + ds * 1024 + lane * 16);
        }
    }

    f32x16 O[4];
#pragma unroll
    for (int et = 0; et < 4; ++et)
#pragma unroll
        for (int i = 0; i < 16; ++i) O[et][i] = 0.f;
    float m = NEGINF, lsum = 0.f;

    const int k0base = split * KSPLIT;

    auto STAGE = [&](int b, int kt) {
        int k0 = k0base + kt * 64;
#pragma unroll
        for (int i = 0; i < 12; ++i) {
            int gg = wv * 12 + i;
            const char* src;
            if (gg < 32) {
                int at = gg >> 4, hl = (gg >> 3) & 1, ds = gg & 7;
                src = KF + ((((size_t)s * 256 + (k0 >> 5) + at) * 2 + hl) * 8 + ds) * 1024
                         + (size_t)lane * 16;
            } else {
                int g2 = gg - 32, ks = g2 >> 2, et = g2 & 3;
                src = VF + ((((size_t)s * 512 + (k0 >> 4) + ks) * 2 + 0) * 4 + et) * 1024
                         + (size_t)lane * 16;
            }
            char* dst = &lds[b][gg * 1024];
            __builtin_amdgcn_global_load_lds(
                (const __attribute__((address_space(1))) void*)src,
                (__attribute__((address_space(3))) void*)dst, 16, 0, 0);
        }
    };

    STAGE(0, 0);
    __syncthreads();

    for (int kt = 0; kt < KTILES; ++kt) {
        const int b = kt & 1;
        if (kt < KTILES - 1) STAGE(b ^ 1, kt + 1);
        const char* Bp = lds[b];

        f32x16 a0, a1;
#pragma unroll
        for (int i = 0; i < 16; ++i) { a0[i] = 0.f; a1[i] = 0.f; }
#pragma unroll
        for (int ds = 0; ds < 8; ++ds) {
            bf16x8 kh0 = *(const bf16x8*)(Bp + (0 + ds) * 1024 + lane * 16);
            bf16x8 kl0 = *(const bf16x8*)(Bp + (8 + ds) * 1024 + lane * 16);
            bf16x8 kh1 = *(const bf16x8*)(Bp + (16 + ds) * 1024 + lane * 16);
            bf16x8 kl1 = *(const bf16x8*)(Bp + (24 + ds) * 1024 + lane * 16);
            bf16x8 qh = u4_to_b8(QH[ds]), ql = u4_to_b8(QL[ds]);
            a0 = MFMA32(kh0, qh, a0);
            a0 = MFMA32(kh0, ql, a0);
            a0 = MFMA32(kl0, qh, a0);
            a1 = MFMA32(kh1, qh, a1);
            a1 = MFMA32(kh1, ql, a1);
            a1 = MFMA32(kl1, qh, a1);
        }

        float tmax = NEGINF;
#pragma unroll
        for (int i = 0; i < 16; ++i) tmax = fmaxf(tmax, fmaxf(a0[i], a1[i]));
        tmax = fmaxf(tmax, __shfl_xor(tmax, 32));
        float mnew = fmaxf(m, tmax);
        float alpha = exp2f((m - mnew) * LOG2E);
        float mn2 = mnew * LOG2E;
        float P[32];
        float tsum = 0.f;
#pragma unroll
        for (int i = 0; i < 16; ++i) { P[i] = exp2f(fmaf(a0[i], LOG2E, -mn2)); tsum += P[i]; }
#pragma unroll
        for (int i = 0; i < 16; ++i) { P[16 + i] = exp2f(fmaf(a1[i], LOG2E, -mn2)); tsum += P[16 + i]; }
        tsum += __shfl_xor(tsum, 32);
        lsum = lsum * alpha + tsum;
        m = mnew;

#pragma unroll
        for (int r = 0; r < 16; ++r) {
            int qrow = (r & 3) + 8 * (r >> 2) + (hh ? 4 : 0);
            float ar = __shfl(alpha, qrow | (hh ? 32 : 0));
#pragma unroll
            for (int et = 0; et < 4; ++et) O[et][r] *= ar;
        }

        unsigned hpk[16];
#pragma unroll
        for (int p = 0; p < 16; ++p) hpk[p] = cvt_pk_bf16(P[2 * p], P[2 * p + 1]);

#pragma unroll
        for (int ks = 0; ks < 4; ++ks) {
            const int i0 = (ks >> 1) * 8 + (ks & 1) * 4;
            unsigned t0 = hh ? hpk[i0 + 2] : hpk[i0];
            unsigned u0 = hh ? hpk[i0] : hpk[i0 + 2];
            unsigned w0 = __shfl_xor(u0, 32);
            unsigned A0 = hh ? w0 : t0;
            unsigned A2 = hh ? t0 : w0;
            unsigned t1 = hh ? hpk[i0 + 3] : hpk[i0 + 1];
            unsigned u1 = hh ? hpk[i0 + 1] : hpk[i0 + 3];
            unsigned w1 = __shfl_xor(u1, 32);
            unsigned A1 = hh ? w1 : t1;
            unsigned A3 = hh ? t1 : w1;

            bf16x8 pa_hi = u4_to_b8(make_uint4(A0, A1, A2, A3));
#pragma unroll
            for (int et = 0; et < 4; ++et) {
                bf16x8 vh = *(const bf16x8*)(Bp + (32 + ks * 4 + et) * 1024 + lane * 16);
                O[et] = MFMA32(pa_hi, vh, O[et]);
            }
        }
        __syncthreads();
    }

    size_t gbase = (size_t)(split * S_ + s) * 512 * 128;
#pragma unroll
    for (int et = 0; et < 4; ++et) {
        int e = et * 32 + l31;
#pragma unroll
        for (int p = 0; p < 8; ++p) {
            int r = 2 * p;
            int qrow = (r & 3) + 8 * (r >> 2) + (hh ? 4 : 0);
            unsigned pk = cvt_pk_bf16(O[et][r], O[et][r + 1]);
            int qh2 = (qt * 128 + wv * 32 + qrow) >> 1;
            Opart[gbase + (size_t)qh2 * 128 + e] = pk;
        }
    }
    if (lane < 32) {
        size_t mb = (size_t)(split * S_ + s) * HW_ + qt * 128 + wv * 32 + lane;
        mpart[mb] = m;
        lpart[mb] = lsum;
    }
}

// ============================================================================
// Merge NSPLIT bf16-pair partials; out[s][e][q]
// ============================================================================
__global__ __launch_bounds__(256)
void cross_combine_kernel(const unsigned* __restrict__ Opart, const float* __restrict__ mpart,
                          const float* __restrict__ lpart, float* __restrict__ out)
{
    const int s = blockIdx.x >> 7;
    const int e = blockIdx.x & 127;
    const int q0 = threadIdx.x * 4;

    float mm[NSPLIT][4];
    float M[4] = {NEGINF, NEGINF, NEGINF, NEGINF};
#pragma unroll
    for (int i = 0; i < NSPLIT; ++i) {
        float4 m4 = *(const float4*)&mpart[(size_t)(i * S_ + s) * HW_ + q0];
        mm[i][0] = m4.x; mm[i][1] = m4.y; mm[i][2] = m4.z; mm[i][3] = m4.w;
#pragma unroll
        for (int j = 0; j < 4; ++j) M[j] = fmaxf(M[j], mm[i][j]);
    }
    float L[4] = {0.f, 0.f, 0.f, 0.f};
    float acc[4] = {0.f, 0.f, 0.f, 0.f};
#pragma unroll
    for (int i = 0; i < NSPLIT; ++i) {
        float4 l4 = *(const float4*)&lpart[(size_t)(i * S_ + s) * HW_ + q0];
        float w0 = expf(mm[i][0] - M[0]);
        float w1 = expf(mm[i][1] - M[1]);
        float w2 = expf(mm[i][2] - M[2]);
        float w3 = expf(mm[i][3] - M[3]);
        L[0] += w0 * l4.x; L[1] += w1 * l4.y; L[2] += w2 * l4.z; L[3] += w3 * l4.w;
        size_t ob = (size_t)(i * S_ + s) * 512 * 128;
        unsigned pa = Opart[ob + (size_t)(q0 >> 1) * 128 + e];
        unsigned pb = Opart[ob + (size_t)((q0 >> 1) + 1) * 128 + e];
        acc[0] += w0 * __uint_as_float(pa << 16);
        acc[1] += w1 * __uint_as_float(pa & 0xffff0000u);
        acc[2] += w2 * __uint_as_float(pb << 16);
        acc[3] += w3 * __uint_as_float(pb & 0xffff0000u);
    }
    float4 o;
    o.x = acc[0] / L[0]; o.y = acc[1] / L[1]; o.z = acc[2] / L[2]; o.w = acc[3] / L[3];
    *(float4*)&out[((size_t)s * CE_ + e) * HW_ + q0] = o;
}

// ============================================================================
extern "C" void kernel_launch(void* const* d_in, const int* in_sizes, int n_in,
                              void* d_out, int out_size, void* d_ws, size_t ws_size,
                              hipStream_t stream) {
    (void)in_sizes; (void)n_in; (void)out_size; (void)ws_size;
    const float* tgt    = (const float*)d_in[0];
    const float* memory = (const float*)d_in[1];
    const float* pe     = (const float*)d_in[2];
    const float* wsw    = (const float*)d_in[3];
    const float* wsb    = (const float*)d_in[4];
    const float* wcw    = (const float*)d_in[5];
    const float* wcb    = (const float*)d_in[6];
    float* out = (float*)d_out;
    float* W = (float*)d_ws;
    char*  PFT   = (char*)(W + O_PFT);
    char*  XV    = (char*)(W + O_XV);
    float* Z     = W + O_Z;
    float* Zn    = W + O_ZN;
    char*  QFc   = (char*)(W + O_QF);
    char*  KFc   = (char*)(W + O_KF);
    char*  VFc   = (char*)(W + O_VF);
    char*  WSF   = (char*)(W + O_WSF);
    char*  WCF   = (char*)(W + O_WCF);
    unsigned* Opart = (unsigned*)(W + O_OPART);  // overlays dead PFT/XV/Z
    float* mpart = W + O_MPART;
    float* lpart = W + O_LPART;

    // weight fragment prep (tiny)
    wconv_kernel<<<dim3(33), 256, 0, stream>>>(wsw, wsb, WSF);
    wconv_kernel<<<dim3(33), 256, 0, stream>>>(wcw, wcb, WCF);
    // self path (fused MFMA flash)
    proj_mfma_kernel<<<dim3(8, 4), 256, 0, stream>>>(tgt, WSF, PFT, HW_, SQRT30);
    xconv_kernel<<<dim3(512), 256, 0, stream>>>(tgt, XV);
    self_flash_mfma<<<dim3(128), 256, 0, stream>>>(PFT, XV, tgt, Z);
    inorm_kernel<<<dim3(S_ * C_), 256, 0, stream>>>(Z, Zn);
    // cross path
    proj_mfma_kernel<<<dim3(8, 4), 256, 0, stream>>>(Zn, WCF, QFc, HW_, 30.0f);
    proj_mfma_kernel<<<dim3(64, 4), 256, 0, stream>>>(memory, WCF, KFc, M_, 1.0f);
    vconv_kernel<<<dim3(2048), 256, 0, stream>>>(pe, VFc);
    cross_flash_mfma<<<dim3(256), 256, 0, stream>>>(QFc, KFc, VFc, Opart, mpart, lpart);
    cross_combine_kernel<<<dim3(S_ * CE_), 256, 0, stream>>>(Opart, mpart, lpart, out);
}